// Round 6
// baseline (782.342 us; speedup 1.0000x reference)
//
#include <hip/hip_runtime.h>
#include <hip/hip_bf16.h>

typedef unsigned short u16;
typedef unsigned int   u32;

// bf16 (stored as u16) <-> f32. Decode exact; encode round-to-nearest-even.
__device__ __forceinline__ float b2f(u16 v){ return __uint_as_float(((u32)v) << 16); }
__device__ __forceinline__ u16   f2b(float f){
  u32 u = __float_as_uint(f);
  u += 0x7fffu + ((u >> 16) & 1u);
  return (u16)(u >> 16);
}
__device__ __forceinline__ float gelu_exact(float x){
  return 0.5f * x * (1.0f + erff(x * 0.70710678118654752440f));
}
// Opaque zero in a VGPR: makes weight addresses "divergent" so the compiler
// emits global_load (vmcnt, deep pipelining, L1 broadcast) instead of
// s_load (lgkmcnt, shallow SGPR pipelining, mixed with ds_read waits).
// All lanes hold 0 -> same address -> TA broadcast; semantics unchanged.
__device__ __forceinline__ int opaque_zero(){
  int z; asm volatile("v_mov_b32 %0, 0" : "=v"(z)); return z;
}

// Workspace float offsets for prepped weight tables (16B-aligned blocks)
#define WTG_OFF   0          // fc1 w1^T: [k][p][28], k<15,p<54 -> 22680 f
#define W2G_OFF   22720      // fc1 w2 padded: [l][s][28], 27 rows -> 11340 f
#define W12G_OFF  34112      // fc2 w1 padded: [k][j][28], 9 rows -> 3780 f
#define PREP_F    37952      // total floats (151808 B, 16B-aligned)

// ---------------------------------------------------------------------------
// K0 (prep): build padded/transposed weight tables in workspace. Runs once.
// ---------------------------------------------------------------------------
__global__ __launch_bounds__(256) void k_prep(
    const float* __restrict__ w1, const float* __restrict__ w2,
    const float* __restrict__ w1_2, float* __restrict__ ws)
{
  int tid = blockIdx.x*256 + threadIdx.x;
  for (int e = tid; e < 15*54*28; e += gridDim.x*256){
    int kk = e / 1512, rem = e - kk*1512;
    int p = rem / 28, j = rem - p*28;
    ws[WTG_OFF + e] = (p < 53 && j < 27) ? w1[(kk*27 + j)*53 + p] : 0.0f;
  }
  for (int e = tid; e < 15*27*28; e += gridDim.x*256){
    int l = e / 756, rem = e - l*756;
    int s = rem / 28, r = rem - s*28;
    ws[W2G_OFF + e] = (r < 27) ? w2[(l*27 + s)*27 + r] : 0.0f;
  }
  for (int e = tid; e < 15*9*28; e += gridDim.x*256){
    int kk = e / 252, rem = e - kk*252;
    int j = rem / 28, p = rem - j*28;
    ws[W12G_OFF + e] = (p < 27) ? w1_2[(kk*9 + j)*27 + p] : 0.0f;
  }
}

// ---------------------------------------------------------------------------
// K1 (fc1a) v6 = v5 + opaque-zero weight base (vector loads on vmcnt).
// v5 post-mortem: VGPR=44/SGPR=112 => weights were s_load'd (lgkmcnt shared
// with ds_read xs) -> shallow pipelining, exposed latency; VALU-busy constant
// 62us across v2-v5, dur = 62/VALUBusy. Moving weights to vmcnt decouples
// counters and enables deep prefetch. FMA order identical -> bit-identical.
// out1[row][f], f=k*27+j = sum_{p<53} xe[row][k*53+p]*w1[k][j][p]
// act column-major bf16: act[f*Bc + row]. Grid (Bc/256, 15), block 256.
// ---------------------------------------------------------------------------
__global__ __launch_bounds__(256, 5) void k_fc1a(
    const float* __restrict__ x, const float* __restrict__ wtg,
    u16* __restrict__ act, int base, int Bc)
{
  __shared__ u32 xsu[256*27];     // row stride 27 u32 (odd -> conflict-free)
  const int tid = threadIdx.x;
  const int k   = blockIdx.y;
  const int rowloc = blockIdx.x * 256;

  // stage x tile: 256 rows x 53 cols as 27 packed-bf16 dwords per row
  #pragma unroll 4
  for (int i = 0; i < 27; ++i){
    int e = i*256 + tid;                 // < 6912
    int r = e / 27, c2 = e - r*27;
    int col = k*53 + 2*c2;               // 2*c2 <= 52 < 53 always
    const size_t rowoff = (size_t)(base + rowloc + r)*784;
    float v0 = 0.f, v1 = 0.f;
    if (col < 784) v0 = x[rowoff + col];
    if (2*c2+1 < 53 && col+1 < 784) v1 = x[rowoff + col + 1];
    xsu[e] = (u32)f2b(v0) | ((u32)f2b(v1) << 16);
  }
  __syncthreads();

  float acc[28];
  #pragma unroll
  for (int j = 0; j < 28; ++j) acc[j] = 0.0f;

  const float* __restrict__ wk = wtg + (size_t)k*1512 + opaque_zero();
  const u32* xrow = &xsu[tid*27];
  #pragma unroll
  for (int pp = 0; pp < 27; ++pp){
    const u32 xv2 = xrow[pp];
    const float x0 = __uint_as_float(xv2 << 16);          // p = 2pp
    const float x1 = __uint_as_float(xv2 & 0xffff0000u);  // p = 2pp+1
    const float4* wa = (const float4*)(wk + 56*pp);       // row 2pp   (28 f)
    const float4* wb = (const float4*)(wk + 56*pp + 28);  // row 2pp+1 (28 f)
    #pragma unroll
    for (int i = 0; i < 7; ++i){
      const float4 a = wa[i];
      const float4 b = wb[i];
      acc[4*i+0] = fmaf(a.x, x0, fmaf(b.x, x1, acc[4*i+0]));
      acc[4*i+1] = fmaf(a.y, x0, fmaf(b.y, x1, acc[4*i+1]));
      acc[4*i+2] = fmaf(a.z, x0, fmaf(b.z, x1, acc[4*i+2]));
      acc[4*i+3] = fmaf(a.w, x0, fmaf(b.w, x1, acc[4*i+3]));
    }
  }
  const int r0 = rowloc + tid;
  #pragma unroll
  for (int j = 0; j < 27; ++j)
    act[(size_t)(k*27 + j)*Bc + r0] = f2b(acc[j]);
}

// ---------------------------------------------------------------------------
// K2 (fc1b) v4 = v3 + opaque-zero weight base. 256 thr, 1 row/thread, no LDS.
// In-place on act: block covers its own rows only -> no cross-block hazard.
// ---------------------------------------------------------------------------
__global__ __launch_bounds__(256) void k_fc1b(
    const float* __restrict__ w2g, const float* __restrict__ b1,
    u16* act, int Bc)
{
  const int tid = threadIdx.x;
  const int l   = blockIdx.y;
  const int row = blockIdx.x*256 + tid;
  const float* __restrict__ wl = w2g + (size_t)l*756 + opaque_zero();

  float t[28];
  #pragma unroll
  for (int r = 0; r < 27; ++r) t[r] = b2f(act[(size_t)(r*15 + l)*Bc + row]);
  t[27] = 0.0f;
  #pragma unroll
  for (int s = 0; s < 27; ++s){
    const float4* wp = (const float4*)(wl + s*28);
    float va = 0.f, vb = 0.f;
    #pragma unroll
    for (int i = 0; i < 7; ++i){
      const float4 w = wp[i];
      va = fmaf(w.x, t[4*i+0], va); vb = fmaf(w.y, t[4*i+1], vb);
      va = fmaf(w.z, t[4*i+2], va); vb = fmaf(w.w, t[4*i+3], vb);
    }
    const int m = s*15 + l;
    const float bb = (m < 392) ? b1[m] : 0.0f;
    const float h = (m < 392) ? gelu_exact(va + vb + bb) : 0.0f;
    act[(size_t)m*Bc + row] = f2b(h);
  }
}

// ---------------------------------------------------------------------------
// K3 (fc2a) v4 = v3 + opaque-zero weight base.
// ---------------------------------------------------------------------------
__global__ __launch_bounds__(256) void k_fc2a(
    const u16* __restrict__ h1t, const float* __restrict__ w12g,
    u16* __restrict__ o2t, int Bc)
{
  const int tid = threadIdx.x;
  const int k   = blockIdx.y;
  const int row = blockIdx.x*256 + tid;
  const float* __restrict__ wk = w12g + (size_t)k*252 + opaque_zero();

  float hb[28];
  #pragma unroll
  for (int p = 0; p < 27; ++p) hb[p] = b2f(h1t[(size_t)(k*27 + p)*Bc + row]);
  hb[27] = 0.0f;
  #pragma unroll
  for (int j = 0; j < 9; ++j){
    const float4* wp = (const float4*)(wk + j*28);
    float va = 0.f, vb = 0.f;
    #pragma unroll
    for (int i = 0; i < 7; ++i){
      const float4 w = wp[i];
      va = fmaf(w.x, hb[4*i+0], va); vb = fmaf(w.y, hb[4*i+1], vb);
      va = fmaf(w.z, hb[4*i+2], va); vb = fmaf(w.w, hb[4*i+3], vb);
    }
    o2t[(size_t)(k*9 + j)*Bc + row] = f2b(va + vb);
  }
}

// ---------------------------------------------------------------------------
// K4 (fc2b) v3 = v2 + opaque-zero weight base.
// ---------------------------------------------------------------------------
__global__ __launch_bounds__(256) void k_fc2b(
    const u16* __restrict__ o2t, const float* __restrict__ w2_2,
    const float* __restrict__ b2, u16* __restrict__ h2t, int Bc)
{
  const int tid = threadIdx.x;
  const int l   = blockIdx.y;
  const float* __restrict__ wl = w2_2 + (size_t)l*81 + opaque_zero();

  const int row = blockIdx.x*256 + tid;
  float t[9];
  #pragma unroll
  for (int r = 0; r < 9; ++r) t[r] = b2f(o2t[(size_t)(r*15 + l)*Bc + row]);
  #pragma unroll
  for (int s = 0; s < 9; ++s){
    float v = 0.f;
    #pragma unroll
    for (int r = 0; r < 9; ++r) v = fmaf(wl[s*9 + r], t[r], v);
    const int m = s*15 + l;
    float h = (m < 128) ? gelu_exact(v + b2[m < 128 ? m : 0]) : 0.0f;
    h2t[(size_t)m*Bc + row] = f2b(h);
  }
}

// ---------------------------------------------------------------------------
// K5 (fc3a) v3 = v2 + opaque-zero weight base.
// ---------------------------------------------------------------------------
__global__ __launch_bounds__(256) void k_fc3a(
    const u16* __restrict__ h2t, const float* __restrict__ w1_3,
    u16* __restrict__ o3t, int Bc)
{
  const int tid = threadIdx.x;
  const int k   = blockIdx.y;
  const float* __restrict__ wk = w1_3 + (size_t)k*45 + opaque_zero();

  const int row = blockIdx.x*256 + tid;
  float hb[9];
  #pragma unroll
  for (int p = 0; p < 9; ++p) hb[p] = b2f(h2t[(size_t)(k*9 + p)*Bc + row]);
  #pragma unroll
  for (int j = 0; j < 5; ++j){
    float v = 0.f;
    #pragma unroll
    for (int p = 0; p < 9; ++p) v = fmaf(wk[j*9 + p], hb[p], v);
    o3t[(size_t)(k*5 + j)*Bc + row] = f2b(v);
  }
}

// ---------------------------------------------------------------------------
// K6 (fc3b + fc4 + log_softmax) v3 = v2 + opaque-zero weight base;
// only outS in LDS for coalesced f32 stores.
// ---------------------------------------------------------------------------
__global__ __launch_bounds__(256) void k_fc3b4(
    const u16* __restrict__ o3t,
    const float* __restrict__ w2_3, const float* __restrict__ b3,
    const float* __restrict__ w1_4, const float* __restrict__ w2_4, const float* __restrict__ b4,
    float* __restrict__ out, int base, int Bc)
{
  __shared__ float outS[256*10];
  const int tid = threadIdx.x;
  const int rloc = blockIdx.x*256 + tid;
  const float* __restrict__ w23 = w2_3 + opaque_zero();

  float sacc[10];
  #pragma unroll
  for (int c = 0; c < 10; ++c) sacc[c] = 0.0f;

  #pragma unroll
  for (int l = 0; l < 15; ++l){
    float t[5];
    #pragma unroll
    for (int r = 0; r < 5; ++r) t[r] = b2f(o3t[(size_t)(r*15 + l)*Bc + rloc]);
    #pragma unroll
    for (int s = 0; s < 5; ++s){
      const int m = s*15 + l;
      if (m < 50){
        const float* wp = w23 + (l*5 + s)*5;
        float v = 0.f;
        v = fmaf(wp[0], t[0], v); v = fmaf(wp[1], t[1], v);
        v = fmaf(wp[2], t[2], v); v = fmaf(wp[3], t[3], v);
        v = fmaf(wp[4], t[4], v);
        const float h = gelu_exact(v + b3[m]);
        const int c = m / 5, p = m - (m/5)*5;      // compile-time constants
        sacc[c] = fmaf(h, w1_4[c*5 + p], sacc[c]);
      }
    }
  }
  float v[10];
  #pragma unroll
  for (int c = 0; c < 10; ++c) v[c] = fmaf(sacc[c], w2_4[c], b4[c]);

  float mx = v[0];
  #pragma unroll
  for (int c = 1; c < 10; ++c) mx = fmaxf(mx, v[c]);
  float sum = 0.f;
  #pragma unroll
  for (int c = 0; c < 10; ++c) sum += expf(v[c] - mx);
  const float lse = mx + logf(sum);
  #pragma unroll
  for (int c = 0; c < 10; ++c) outS[tid*10 + c] = v[c] - lse;
  __syncthreads();
  const size_t blockOut = (size_t)(base + blockIdx.x*256) * 10;
  #pragma unroll
  for (int i = 0; i < 10; ++i){
    int e = i*256 + tid;
    out[blockOut + e] = outS[e];
  }
}

// ---------------------------------------------------------------------------
extern "C" void kernel_launch(void* const* d_in, const int* in_sizes, int n_in,
                              void* d_out, int out_size, void* d_ws, size_t ws_size,
                              hipStream_t stream)
{
  const float* x     = (const float*)d_in[0];
  const float* f1w1  = (const float*)d_in[1];
  const float* f1w2  = (const float*)d_in[2];
  const float* f1b   = (const float*)d_in[3];
  const float* f2w1  = (const float*)d_in[4];
  const float* f2w2  = (const float*)d_in[5];
  const float* f2b   = (const float*)d_in[6];
  const float* f3w1  = (const float*)d_in[7];
  const float* f3w2  = (const float*)d_in[8];
  const float* f3b   = (const float*)d_in[9];
  const float* f4w1  = (const float*)d_in[10];
  const float* f4w2  = (const float*)d_in[11];
  const float* f4b   = (const float*)d_in[12];
  const int B = in_sizes[0] / 784;           // 65536
  (void)n_in; (void)out_size;

  // ws layout: [prep tables: PREP_F floats = 151808 B]
  //            [act 405 | o2t 135 | h2t 135 | o3t 75 u16 per row = 1500 B/row]
  const size_t prepBytes = (size_t)PREP_F * sizeof(float);
  float* wsF  = (float*)d_ws;
  u16*  wsAct = (u16*)((char*)d_ws + prepBytes);

  k_prep<<<dim3(32), 256, 0, stream>>>(f1w1, f1w2, f2w1, wsF);

  const float* wtg  = wsF + WTG_OFF;
  const float* w2g  = wsF + W2G_OFF;
  const float* w12g = wsF + W12G_OFF;

  const size_t perRow = 750 * sizeof(u16);
  int Rc = B;
  if (ws_size - prepBytes < (size_t)B * perRow){
    size_t rows = (ws_size - prepBytes) / perRow;
    Rc = (int)(rows & ~(size_t)511);
    if (Rc < 512) Rc = 512;
  }
  for (int base = 0; base < B; base += Rc){
    const int Bc = (B - base < Rc) ? (B - base) : Rc;
    u16* act = wsAct;
    u16* o2t = act + (size_t)405 * Bc;
    u16* h2t = o2t + (size_t)135 * Bc;
    u16* o3t = h2t + (size_t)135 * Bc;
    k_fc1a<<<dim3(Bc/256, 15), 256, 0, stream>>>(x, wtg, act, base, Bc);
    k_fc1b<<<dim3(Bc/256, 15), 256, 0, stream>>>(w2g, f1b, act, Bc);
    k_fc2a<<<dim3(Bc/256, 15), 256, 0, stream>>>(act, w12g, o2t, Bc);
    k_fc2b<<<dim3(Bc/256, 15), 256, 0, stream>>>(o2t, f2w2, f2b, h2t, Bc);
    k_fc3a<<<dim3(Bc/256, 15), 256, 0, stream>>>(h2t, f3w1, o3t, Bc);
    k_fc3b4<<<dim3(Bc/256), 256, 0, stream>>>(o3t, f3w2, f3b,
                                              f4w1, f4w2, f4b, (float*)d_out, base, Bc);
  }
}

// Round 7
// 505.688 us; speedup vs baseline: 1.5471x; 1.5471x over previous
//
#include <hip/hip_runtime.h>
#include <hip/hip_bf16.h>

typedef unsigned short u16;
typedef unsigned int   u32;

// bf16 (stored as u16) <-> f32. Decode exact; encode round-to-nearest-even.
__device__ __forceinline__ float b2f(u16 v){ return __uint_as_float(((u32)v) << 16); }
__device__ __forceinline__ u16   f2b(float f){
  u32 u = __float_as_uint(f);
  u += 0x7fffu + ((u >> 16) & 1u);
  return (u16)(u >> 16);
}
// bf16 round-trip (quantize like a store+load through a bf16 buffer)
__device__ __forceinline__ float bfrt(float f){ return b2f(f2b(f)); }
__device__ __forceinline__ float gelu_exact(float x){
  return 0.5f * x * (1.0f + erff(x * 0.70710678118654752440f));
}

// Workspace float offsets for prepped weight tables (16B-aligned blocks)
#define WTG_OFF   0          // fc1 w1^T: [k][p][28], k<15,p<54 -> 22680 f
#define W2G_OFF   22720      // fc1 w2 padded: [l][s][28], 27 rows -> 11340 f
#define W12G_OFF  34112      // fc2 w1 padded: [k][j][28], 9 rows -> 3780 f
#define PREP_F    37952      // total floats (151808 B, 16B-aligned)

// ---------------------------------------------------------------------------
// K0 (prep): build padded/transposed weight tables in workspace. Runs once.
// ---------------------------------------------------------------------------
__global__ __launch_bounds__(256) void k_prep(
    const float* __restrict__ w1, const float* __restrict__ w2,
    const float* __restrict__ w1_2, float* __restrict__ ws)
{
  int tid = blockIdx.x*256 + threadIdx.x;
  for (int e = tid; e < 15*54*28; e += gridDim.x*256){
    int kk = e / 1512, rem = e - kk*1512;
    int p = rem / 28, j = rem - p*28;
    ws[WTG_OFF + e] = (p < 53 && j < 27) ? w1[(kk*27 + j)*53 + p] : 0.0f;
  }
  for (int e = tid; e < 15*27*28; e += gridDim.x*256){
    int l = e / 756, rem = e - l*756;
    int s = rem / 28, r = rem - s*28;
    ws[W2G_OFF + e] = (r < 27) ? w2[(l*27 + s)*27 + r] : 0.0f;
  }
  for (int e = tid; e < 15*9*28; e += gridDim.x*256){
    int kk = e / 252, rem = e - kk*252;
    int j = rem / 28, p = rem - j*28;
    ws[W12G_OFF + e] = (p < 27) ? w1_2[(kk*9 + j)*27 + p] : 0.0f;
  }
}

// ---------------------------------------------------------------------------
// K1 (fc1a) v7 == v5 exact revert (known 138us, occ 52%, VALU 45%).
// v6 post-mortem: opaque-zero vector weight loads (same addr in all lanes)
// exploded TCC traffic (WRITE 51.8->387MB, FETCH 111->215MB): wave-uniform
// data must stay on the scalar path. s_load latency is the accepted cost.
// out1[row][f], f=k*27+j = sum_{p<53} xe[row][k*53+p]*w1[k][j][p]
// act column-major bf16: act[f*Bc + row]. Grid (Bc/256, 15), block 256.
// ---------------------------------------------------------------------------
__global__ __launch_bounds__(256, 5) void k_fc1a(
    const float* __restrict__ x, const float* __restrict__ wtg,
    u16* __restrict__ act, int base, int Bc)
{
  __shared__ u32 xsu[256*27];     // row stride 27 u32 (odd -> conflict-free)
  const int tid = threadIdx.x;
  const int k   = blockIdx.y;
  const int rowloc = blockIdx.x * 256;

  // stage x tile: 256 rows x 53 cols as 27 packed-bf16 dwords per row
  #pragma unroll 4
  for (int i = 0; i < 27; ++i){
    int e = i*256 + tid;                 // < 6912
    int r = e / 27, c2 = e - r*27;
    int col = k*53 + 2*c2;               // 2*c2 <= 52 < 53 always
    const size_t rowoff = (size_t)(base + rowloc + r)*784;
    float v0 = 0.f, v1 = 0.f;
    if (col < 784) v0 = x[rowoff + col];
    if (2*c2+1 < 53 && col+1 < 784) v1 = x[rowoff + col + 1];
    xsu[e] = (u32)f2b(v0) | ((u32)f2b(v1) << 16);
  }
  __syncthreads();

  float acc[28];
  #pragma unroll
  for (int j = 0; j < 28; ++j) acc[j] = 0.0f;

  const float* __restrict__ wk = wtg + (size_t)k*1512;   // 54*28
  const u32* xrow = &xsu[tid*27];
  #pragma unroll
  for (int pp = 0; pp < 27; ++pp){
    const u32 xv2 = xrow[pp];
    const float x0 = __uint_as_float(xv2 << 16);          // p = 2pp
    const float x1 = __uint_as_float(xv2 & 0xffff0000u);  // p = 2pp+1
    const float4* wa = (const float4*)(wk + 56*pp);       // row 2pp   (28 f)
    const float4* wb = (const float4*)(wk + 56*pp + 28);  // row 2pp+1 (28 f)
    #pragma unroll
    for (int i = 0; i < 7; ++i){
      const float4 a = wa[i];
      const float4 b = wb[i];
      acc[4*i+0] = fmaf(a.x, x0, fmaf(b.x, x1, acc[4*i+0]));
      acc[4*i+1] = fmaf(a.y, x0, fmaf(b.y, x1, acc[4*i+1]));
      acc[4*i+2] = fmaf(a.z, x0, fmaf(b.z, x1, acc[4*i+2]));
      acc[4*i+3] = fmaf(a.w, x0, fmaf(b.w, x1, acc[4*i+3]));
    }
  }
  const int r0 = rowloc + tid;
  #pragma unroll
  for (int j = 0; j < 27; ++j)
    act[(size_t)(k*27 + j)*Bc + r0] = f2b(acc[j]);
}

// ---------------------------------------------------------------------------
// K2 (fc1b) v5 == round-5 v3 revert. 256 thr, 1 row/thread, scalar weights.
// In-place on act: block covers its own rows only -> no cross-block hazard.
// ---------------------------------------------------------------------------
__global__ __launch_bounds__(256) void k_fc1b(
    const float* __restrict__ w2g, const float* __restrict__ b1,
    u16* act, int Bc)
{
  const int tid = threadIdx.x;
  const int l   = blockIdx.y;
  const int row = blockIdx.x*256 + tid;
  const float* __restrict__ wl = w2g + (size_t)l*756;   // 27*28

  float t[28];
  #pragma unroll
  for (int r = 0; r < 27; ++r) t[r] = b2f(act[(size_t)(r*15 + l)*Bc + row]);
  t[27] = 0.0f;
  #pragma unroll
  for (int s = 0; s < 27; ++s){
    const float4* wp = (const float4*)(wl + s*28);
    float va = 0.f, vb = 0.f;
    #pragma unroll
    for (int i = 0; i < 7; ++i){
      const float4 w = wp[i];
      va = fmaf(w.x, t[4*i+0], va); vb = fmaf(w.y, t[4*i+1], vb);
      va = fmaf(w.z, t[4*i+2], va); vb = fmaf(w.w, t[4*i+3], vb);
    }
    const int m = s*15 + l;
    const float bb = (m < 392) ? b1[m] : 0.0f;
    const float h = (m < 392) ? gelu_exact(va + vb + bb) : 0.0f;
    act[(size_t)m*Bc + row] = f2b(h);
  }
}

// ---------------------------------------------------------------------------
// K3 (fc2a) v5 == round-5 v3 revert. 256 thr, 1 row/thread, scalar weights.
// ---------------------------------------------------------------------------
__global__ __launch_bounds__(256) void k_fc2a(
    const u16* __restrict__ h1t, const float* __restrict__ w12g,
    u16* __restrict__ o2t, int Bc)
{
  const int tid = threadIdx.x;
  const int k   = blockIdx.y;
  const int row = blockIdx.x*256 + tid;
  const float* __restrict__ wk = w12g + (size_t)k*252;  // 9*28

  float hb[28];
  #pragma unroll
  for (int p = 0; p < 27; ++p) hb[p] = b2f(h1t[(size_t)(k*27 + p)*Bc + row]);
  hb[27] = 0.0f;
  #pragma unroll
  for (int j = 0; j < 9; ++j){
    const float4* wp = (const float4*)(wk + j*28);
    float va = 0.f, vb = 0.f;
    #pragma unroll
    for (int i = 0; i < 7; ++i){
      const float4 w = wp[i];
      va = fmaf(w.x, hb[4*i+0], va); vb = fmaf(w.y, hb[4*i+1], vb);
      va = fmaf(w.z, hb[4*i+2], va); vb = fmaf(w.w, hb[4*i+3], vb);
    }
    o2t[(size_t)(k*9 + j)*Bc + row] = f2b(va + vb);
  }
}

// ---------------------------------------------------------------------------
// K4 (tail) NEW: fc2b + fc3a + fc3b4 fused, one row/thread, grid Bc/256.
// The three former kernels are latency-bound passes over tiny data; their
// intermediates (h2: 128+7 zeros, o3: 75) fit in registers with STATIC
// indexing (all loops unrolled). Former kernel boundaries' bf16 round-trips
// preserved via bfrt() -> bit-identical output. Saves ~55MB of h2t/o3t HBM
// round-trip + two kernel-wide latency passes.
// ---------------------------------------------------------------------------
__global__ __launch_bounds__(256) void k_tail(
    const u16* __restrict__ o2t,
    const float* __restrict__ w2_2, const float* __restrict__ b2,
    const float* __restrict__ w1_3,
    const float* __restrict__ w2_3, const float* __restrict__ b3,
    const float* __restrict__ w1_4, const float* __restrict__ w2_4, const float* __restrict__ b4,
    float* __restrict__ out, int base, int Bc)
{
  __shared__ float outS[256*10];
  const int tid = threadIdx.x;
  const int row = blockIdx.x*256 + tid;

  // ---- fc2b: h2[m], m = s*15+l; m>=128 are zeros (static) ----
  float h2[135];
  #pragma unroll
  for (int l = 0; l < 15; ++l){
    float t[9];
    #pragma unroll
    for (int r = 0; r < 9; ++r) t[r] = b2f(o2t[(size_t)(r*15 + l)*Bc + row]);
    #pragma unroll
    for (int s = 0; s < 9; ++s){
      const int m = s*15 + l;
      float v = 0.f;
      #pragma unroll
      for (int r = 0; r < 9; ++r) v = fmaf(w2_2[l*81 + s*9 + r], t[r], v);
      const float h = (m < 128) ? gelu_exact(v + b2[m < 128 ? m : 0]) : 0.0f;
      h2[m] = bfrt(h);                    // == b2f(f2b(h)) store/load parity
    }
  }

  // ---- fc3a: o3[col], col = k2*5+j ----
  float o3[75];
  #pragma unroll
  for (int k2 = 0; k2 < 15; ++k2){
    #pragma unroll
    for (int j = 0; j < 5; ++j){
      float v = 0.f;
      #pragma unroll
      for (int p = 0; p < 9; ++p) v = fmaf(w1_3[k2*45 + j*9 + p], h2[k2*9 + p], v);
      o3[k2*5 + j] = bfrt(v);
    }
  }

  // ---- fc3b + fc4 + log_softmax (identical to former k_fc3b4 body) ----
  float sacc[10];
  #pragma unroll
  for (int c = 0; c < 10; ++c) sacc[c] = 0.0f;

  #pragma unroll
  for (int l = 0; l < 15; ++l){
    float t[5];
    #pragma unroll
    for (int r = 0; r < 5; ++r) t[r] = o3[r*15 + l];   // static reg index
    #pragma unroll
    for (int s = 0; s < 5; ++s){
      const int m = s*15 + l;
      if (m < 50){
        const float* wp = w2_3 + (l*5 + s)*5;
        float v = 0.f;
        v = fmaf(wp[0], t[0], v); v = fmaf(wp[1], t[1], v);
        v = fmaf(wp[2], t[2], v); v = fmaf(wp[3], t[3], v);
        v = fmaf(wp[4], t[4], v);
        const float h = gelu_exact(v + b3[m]);
        const int c = m / 5, p = m - (m/5)*5;      // compile-time constants
        sacc[c] = fmaf(h, w1_4[c*5 + p], sacc[c]);
      }
    }
  }
  float v[10];
  #pragma unroll
  for (int c = 0; c < 10; ++c) v[c] = fmaf(sacc[c], w2_4[c], b4[c]);

  float mx = v[0];
  #pragma unroll
  for (int c = 1; c < 10; ++c) mx = fmaxf(mx, v[c]);
  float sum = 0.f;
  #pragma unroll
  for (int c = 0; c < 10; ++c) sum += expf(v[c] - mx);
  const float lse = mx + logf(sum);
  #pragma unroll
  for (int c = 0; c < 10; ++c) outS[tid*10 + c] = v[c] - lse;
  __syncthreads();
  const size_t blockOut = (size_t)(base + blockIdx.x*256) * 10;
  #pragma unroll
  for (int i = 0; i < 10; ++i){
    int e = i*256 + tid;
    out[blockOut + e] = outS[e];
  }
}

// ---------------------------------------------------------------------------
extern "C" void kernel_launch(void* const* d_in, const int* in_sizes, int n_in,
                              void* d_out, int out_size, void* d_ws, size_t ws_size,
                              hipStream_t stream)
{
  const float* x     = (const float*)d_in[0];
  const float* f1w1  = (const float*)d_in[1];
  const float* f1w2  = (const float*)d_in[2];
  const float* f1b   = (const float*)d_in[3];
  const float* f2w1  = (const float*)d_in[4];
  const float* f2w2  = (const float*)d_in[5];
  const float* f2b   = (const float*)d_in[6];
  const float* f3w1  = (const float*)d_in[7];
  const float* f3w2  = (const float*)d_in[8];
  const float* f3b   = (const float*)d_in[9];
  const float* f4w1  = (const float*)d_in[10];
  const float* f4w2  = (const float*)d_in[11];
  const float* f4b   = (const float*)d_in[12];
  const int B = in_sizes[0] / 784;           // 65536
  (void)n_in; (void)out_size;

  // ws layout: [prep tables: PREP_F floats = 151808 B]
  //            [act 405 | o2t 135 u16 per row = 1080 B/row]
  const size_t prepBytes = (size_t)PREP_F * sizeof(float);
  float* wsF  = (float*)d_ws;
  u16*  wsAct = (u16*)((char*)d_ws + prepBytes);

  k_prep<<<dim3(32), 256, 0, stream>>>(f1w1, f1w2, f2w1, wsF);

  const float* wtg  = wsF + WTG_OFF;
  const float* w2g  = wsF + W2G_OFF;
  const float* w12g = wsF + W12G_OFF;

  const size_t perRow = 540 * sizeof(u16);   // act 405 + o2t 135
  int Rc = B;
  if (ws_size - prepBytes < (size_t)B * perRow){
    size_t rows = (ws_size - prepBytes) / perRow;
    Rc = (int)(rows & ~(size_t)511);
    if (Rc < 512) Rc = 512;
  }
  for (int base = 0; base < B; base += Rc){
    const int Bc = (B - base < Rc) ? (B - base) : Rc;
    u16* act = wsAct;
    u16* o2t = act + (size_t)405 * Bc;
    k_fc1a<<<dim3(Bc/256, 15), 256, 0, stream>>>(x, wtg, act, base, Bc);
    k_fc1b<<<dim3(Bc/256, 15), 256, 0, stream>>>(w2g, f1b, act, Bc);
    k_fc2a<<<dim3(Bc/256, 15), 256, 0, stream>>>(act, w12g, o2t, Bc);
    k_tail<<<dim3(Bc/256), 256, 0, stream>>>(o2t, f2w2, f2b, f3w1,
                                             f3w2, f3b, f4w1, f4w2, f4b,
                                             (float*)d_out, base, Bc);
  }
}

// Round 8
// 484.909 us; speedup vs baseline: 1.6134x; 1.0429x over previous
//
#include <hip/hip_runtime.h>
#include <hip/hip_bf16.h>

typedef unsigned short u16;
typedef unsigned int   u32;
typedef __attribute__((ext_vector_type(8))) short short8;   // 8 bf16 (4 VGPRs)
typedef __attribute__((ext_vector_type(4))) float f32x4;    // MFMA C/D

// bf16 (stored as u16) <-> f32. Decode exact; encode round-to-nearest-even.
__device__ __forceinline__ float b2f(u16 v){ return __uint_as_float(((u32)v) << 16); }
__device__ __forceinline__ u16   f2b(float f){
  u32 u = __float_as_uint(f);
  u += 0x7fffu + ((u >> 16) & 1u);
  return (u16)(u >> 16);
}
__device__ __forceinline__ float gelu_exact(float x){
  return 0.5f * x * (1.0f + erff(x * 0.70710678118654752440f));
}

// Workspace layout:
//  floats: [w2g 11340 | w12g 3780] = 15120 f (60480 B)
//  u16   : wfrag (fc1 w1 MFMA fragments, hi/lo double-bf16) 61440 u16 (122880 B)
//  then  : per-chunk act/o2t/h2t/o3t streams
#define W2G_OFF   0
#define W12G_OFF  11340
#define PREP_F    15120
#define WFRAG_U16 61440     // 15 k * 2 s * 2 ct * 2 part * 512
#define PREP_BYTES (PREP_F*4 + WFRAG_U16*2)   // 183360

// ---------------------------------------------------------------------------
// K0 (prep): padded weight tables for fc1b/fc2a + MFMA fragment table for
// fc1a. Fragment layout (mfma_f32_16x16x32_bf16 B-operand): lane l holds
// B[k=(l>>4)*8+i][col=l&15]; stored hi then lo (double-bf16: w = hi + lo).
// ---------------------------------------------------------------------------
__global__ __launch_bounds__(256) void k_prep(
    const float* __restrict__ w1, const float* __restrict__ w2,
    const float* __restrict__ w1_2, float* __restrict__ wsF,
    u16* __restrict__ wfrag)
{
  int tid = blockIdx.x*256 + threadIdx.x;
  for (int e = tid; e < 15*27*28; e += gridDim.x*256){
    int l = e / 756, rem = e - l*756;
    int s = rem / 28, r = rem - s*28;
    wsF[W2G_OFF + e] = (r < 27) ? w2[(l*27 + s)*27 + r] : 0.0f;
  }
  for (int e = tid; e < 15*9*28; e += gridDim.x*256){
    int kk = e / 252, rem = e - kk*252;
    int j = rem / 28, p = rem - j*28;
    wsF[W12G_OFF + e] = (p < 27) ? w1_2[(kk*9 + j)*27 + p] : 0.0f;
  }
  // fc1a fragments: 15*2*2*512 = 30720 slots; each writes hi and lo.
  for (int e = tid; e < 30720; e += gridDim.x*256){
    int k  = e / 2048, rem = e - k*2048;
    int s  = rem / 1024; rem -= s*1024;
    int ct = rem / 512;  int sl = rem - ct*512;
    int lane = sl / 8, i = sl - lane*8;
    int p = s*32 + (lane >> 4)*8 + i;        // K index (0..63; real <53)
    int j = ct*16 + (lane & 15);             // col   (0..31; real <27)
    float wv = (p < 53 && j < 27) ? w1[(k*27 + j)*53 + p] : 0.0f;
    u16 hi = f2b(wv);
    u16 lo = f2b(wv - b2f(hi));
    int bidx = (k*2 + s)*2 + ct;
    wfrag[bidx*1024 + sl]       = hi;
    wfrag[bidx*1024 + 512 + sl] = lo;
  }
}

// ---------------------------------------------------------------------------
// K1 (fc1a) v8: MFMA 16x16x32 bf16. Per block (256 thr = 4 waves, k=by):
// stage 256 rows x 64-K bf16 x-tile in LDS (stride 72 u16: 2-way-max banks,
// 36 KB -> 4 blocks/CU); wave w handles rows w*64..+63 = 4 row-tiles x
// 2 col-tiles x 2 K-steps; weights double-bf16 (hi+lo) -> weight error ~f32.
// v5-v7 showed the scalar path has a conserved ~62us VALU floor (MfmaUtil 0);
// MFMA makes compute ~0 and leaves the kernel HBM/L3-bound (~26-41us floor).
// A-frag: lane holds A[l&15][(l>>4)*8+i]; C/D: col=l&15, row=(l>>4)*4+reg.
// ---------------------------------------------------------------------------
__global__ __launch_bounds__(256, 4) void k_fc1a(
    const float* __restrict__ x, const u16* __restrict__ wfrag,
    u16* __restrict__ act, int base, int Bc)
{
  __shared__ __align__(16) u16 xs[256*72];   // [row][72] bf16, cols 53..71 = 0
  const int tid = threadIdx.x;
  const int k   = blockIdx.y;
  const int rowloc = blockIdx.x * 256;

  // stage x tile as packed bf16 pairs: 256 rows x 36 dwords
  u32* xsu = (u32*)xs;
  #pragma unroll 4
  for (int i = 0; i < 36; ++i){
    int e = i*256 + tid;                 // < 9216
    int r = e / 36, c2 = e - r*36;
    int col = k*53 + 2*c2;
    const size_t rowoff = (size_t)(base + rowloc + r)*784;
    float v0 = 0.f, v1 = 0.f;
    if (2*c2   < 53 && col   < 784) v0 = x[rowoff + col];
    if (2*c2+1 < 53 && col+1 < 784) v1 = x[rowoff + col + 1];
    xsu[e] = (u32)f2b(v0) | ((u32)f2b(v1) << 16);
  }
  __syncthreads();

  const int lane = tid & 63;
  const int w    = tid >> 6;
  const int lrow = lane & 15;          // A row within tile / C col within tile
  const int lgrp = lane >> 4;          // 0..3

  f32x4 acc[4][2];
  #pragma unroll
  for (int t = 0; t < 4; ++t){
    #pragma unroll
    for (int c = 0; c < 2; ++c) acc[t][c] = (f32x4){0.f,0.f,0.f,0.f};
  }

  #pragma unroll
  for (int s = 0; s < 2; ++s){
    // B fragments (hi/lo for both col-tiles), coalesced per-lane loads
    const u16* fb = wfrag + ((k*2 + s)*2)*1024;
    const short8 bh0 = *(const short8*)(fb +         lane*8);
    const short8 bl0 = *(const short8*)(fb +  512 +  lane*8);
    const short8 bh1 = *(const short8*)(fb + 1024 +  lane*8);
    const short8 bl1 = *(const short8*)(fb + 1536 +  lane*8);
    #pragma unroll
    for (int t = 0; t < 4; ++t){
      const short8 av = *(const short8*)&xs[(w*64 + t*16 + lrow)*72 + s*32 + lgrp*8];
      acc[t][0] = __builtin_amdgcn_mfma_f32_16x16x32_bf16(av, bh0, acc[t][0], 0, 0, 0);
      acc[t][0] = __builtin_amdgcn_mfma_f32_16x16x32_bf16(av, bl0, acc[t][0], 0, 0, 0);
      acc[t][1] = __builtin_amdgcn_mfma_f32_16x16x32_bf16(av, bh1, acc[t][1], 0, 0, 0);
      acc[t][1] = __builtin_amdgcn_mfma_f32_16x16x32_bf16(av, bl1, acc[t][1], 0, 0, 0);
    }
  }

  // writeback: lane owns col = ct*16 + lrow, rows (w*64 + t*16 + lgrp*4 +0..3)
  #pragma unroll
  for (int ct = 0; ct < 2; ++ct){
    const int col = ct*16 + lrow;
    if (col < 27){
      #pragma unroll
      for (int t = 0; t < 4; ++t){
        const f32x4 a = acc[t][ct];
        u32 lo = (u32)f2b(a.x) | ((u32)f2b(a.y) << 16);
        u32 hi = (u32)f2b(a.z) | ((u32)f2b(a.w) << 16);
        const size_t idx = (size_t)(k*27 + col)*Bc + rowloc + w*64 + t*16 + lgrp*4;
        *(uint2*)&act[idx] = make_uint2(lo, hi);
      }
    }
  }
}

// ---------------------------------------------------------------------------
// K2 (fc1b) == round-5 config (462us total). 256 thr, 1 row/thread, scalar
// (s_load) weights. In-place on act: block covers its own rows only.
// ---------------------------------------------------------------------------
__global__ __launch_bounds__(256) void k_fc1b(
    const float* __restrict__ w2g, const float* __restrict__ b1,
    u16* act, int Bc)
{
  const int tid = threadIdx.x;
  const int l   = blockIdx.y;
  const int row = blockIdx.x*256 + tid;
  const float* __restrict__ wl = w2g + (size_t)l*756;   // 27*28

  float t[28];
  #pragma unroll
  for (int r = 0; r < 27; ++r) t[r] = b2f(act[(size_t)(r*15 + l)*Bc + row]);
  t[27] = 0.0f;
  #pragma unroll
  for (int s = 0; s < 27; ++s){
    const float4* wp = (const float4*)(wl + s*28);
    float va = 0.f, vb = 0.f;
    #pragma unroll
    for (int i = 0; i < 7; ++i){
      const float4 w = wp[i];
      va = fmaf(w.x, t[4*i+0], va); vb = fmaf(w.y, t[4*i+1], vb);
      va = fmaf(w.z, t[4*i+2], va); vb = fmaf(w.w, t[4*i+3], vb);
    }
    const int m = s*15 + l;
    const float bb = (m < 392) ? b1[m] : 0.0f;
    const float h = (m < 392) ? gelu_exact(va + vb + bb) : 0.0f;
    act[(size_t)m*Bc + row] = f2b(h);
  }
}

// ---------------------------------------------------------------------------
// K3 (fc2a) == round-5 config.
// ---------------------------------------------------------------------------
__global__ __launch_bounds__(256) void k_fc2a(
    const u16* __restrict__ h1t, const float* __restrict__ w12g,
    u16* __restrict__ o2t, int Bc)
{
  const int tid = threadIdx.x;
  const int k   = blockIdx.y;
  const int row = blockIdx.x*256 + tid;
  const float* __restrict__ wk = w12g + (size_t)k*252;  // 9*28

  float hb[28];
  #pragma unroll
  for (int p = 0; p < 27; ++p) hb[p] = b2f(h1t[(size_t)(k*27 + p)*Bc + row]);
  hb[27] = 0.0f;
  #pragma unroll
  for (int j = 0; j < 9; ++j){
    const float4* wp = (const float4*)(wk + j*28);
    float va = 0.f, vb = 0.f;
    #pragma unroll
    for (int i = 0; i < 7; ++i){
      const float4 w = wp[i];
      va = fmaf(w.x, hb[4*i+0], va); vb = fmaf(w.y, hb[4*i+1], vb);
      va = fmaf(w.z, hb[4*i+2], va); vb = fmaf(w.w, hb[4*i+3], vb);
    }
    o2t[(size_t)(k*9 + j)*Bc + row] = f2b(va + vb);
  }
}

// ---------------------------------------------------------------------------
// K4 (fc2b) == round-5 config.
// ---------------------------------------------------------------------------
__global__ __launch_bounds__(256) void k_fc2b(
    const u16* __restrict__ o2t, const float* __restrict__ w2_2,
    const float* __restrict__ b2, u16* __restrict__ h2t, int Bc)
{
  const int tid = threadIdx.x;
  const int l   = blockIdx.y;
  const float* __restrict__ wl = w2_2 + (size_t)l*81;

  const int row = blockIdx.x*256 + tid;
  float t[9];
  #pragma unroll
  for (int r = 0; r < 9; ++r) t[r] = b2f(o2t[(size_t)(r*15 + l)*Bc + row]);
  #pragma unroll
  for (int s = 0; s < 9; ++s){
    float v = 0.f;
    #pragma unroll
    for (int r = 0; r < 9; ++r) v = fmaf(wl[s*9 + r], t[r], v);
    const int m = s*15 + l;
    float h = (m < 128) ? gelu_exact(v + b2[m < 128 ? m : 0]) : 0.0f;
    h2t[(size_t)m*Bc + row] = f2b(h);
  }
}

// ---------------------------------------------------------------------------
// K5 (fc3a) == round-5 config.
// ---------------------------------------------------------------------------
__global__ __launch_bounds__(256) void k_fc3a(
    const u16* __restrict__ h2t, const float* __restrict__ w1_3,
    u16* __restrict__ o3t, int Bc)
{
  const int tid = threadIdx.x;
  const int k   = blockIdx.y;
  const float* __restrict__ wk = w1_3 + (size_t)k*45;

  const int row = blockIdx.x*256 + tid;
  float hb[9];
  #pragma unroll
  for (int p = 0; p < 9; ++p) hb[p] = b2f(h2t[(size_t)(k*9 + p)*Bc + row]);
  #pragma unroll
  for (int j = 0; j < 5; ++j){
    float v = 0.f;
    #pragma unroll
    for (int p = 0; p < 9; ++p) v = fmaf(wk[j*9 + p], hb[p], v);
    o3t[(size_t)(k*5 + j)*Bc + row] = f2b(v);
  }
}

// ---------------------------------------------------------------------------
// K6 (fc3b + fc4 + log_softmax) == round-5 config.
// ---------------------------------------------------------------------------
__global__ __launch_bounds__(256) void k_fc3b4(
    const u16* __restrict__ o3t,
    const float* __restrict__ w2_3, const float* __restrict__ b3,
    const float* __restrict__ w1_4, const float* __restrict__ w2_4, const float* __restrict__ b4,
    float* __restrict__ out, int base, int Bc)
{
  __shared__ float outS[256*10];
  const int tid = threadIdx.x;
  const int rloc = blockIdx.x*256 + tid;

  float sacc[10];
  #pragma unroll
  for (int c = 0; c < 10; ++c) sacc[c] = 0.0f;

  #pragma unroll
  for (int l = 0; l < 15; ++l){
    float t[5];
    #pragma unroll
    for (int r = 0; r < 5; ++r) t[r] = b2f(o3t[(size_t)(r*15 + l)*Bc + rloc]);
    #pragma unroll
    for (int s = 0; s < 5; ++s){
      const int m = s*15 + l;
      if (m < 50){
        const float* wp = w2_3 + (l*5 + s)*5;
        float v = 0.f;
        v = fmaf(wp[0], t[0], v); v = fmaf(wp[1], t[1], v);
        v = fmaf(wp[2], t[2], v); v = fmaf(wp[3], t[3], v);
        v = fmaf(wp[4], t[4], v);
        const float h = gelu_exact(v + b3[m]);
        const int c = m / 5, p = m - (m/5)*5;      // compile-time constants
        sacc[c] = fmaf(h, w1_4[c*5 + p], sacc[c]);
      }
    }
  }
  float v[10];
  #pragma unroll
  for (int c = 0; c < 10; ++c) v[c] = fmaf(sacc[c], w2_4[c], b4[c]);

  float mx = v[0];
  #pragma unroll
  for (int c = 1; c < 10; ++c) mx = fmaxf(mx, v[c]);
  float sum = 0.f;
  #pragma unroll
  for (int c = 0; c < 10; ++c) sum += expf(v[c] - mx);
  const float lse = mx + logf(sum);
  #pragma unroll
  for (int c = 0; c < 10; ++c) outS[tid*10 + c] = v[c] - lse;
  __syncthreads();
  const size_t blockOut = (size_t)(base + blockIdx.x*256) * 10;
  #pragma unroll
  for (int i = 0; i < 10; ++i){
    int e = i*256 + tid;
    out[blockOut + e] = outS[e];
  }
}

// ---------------------------------------------------------------------------
extern "C" void kernel_launch(void* const* d_in, const int* in_sizes, int n_in,
                              void* d_out, int out_size, void* d_ws, size_t ws_size,
                              hipStream_t stream)
{
  const float* x     = (const float*)d_in[0];
  const float* f1w1  = (const float*)d_in[1];
  const float* f1w2  = (const float*)d_in[2];
  const float* f1b   = (const float*)d_in[3];
  const float* f2w1  = (const float*)d_in[4];
  const float* f2w2  = (const float*)d_in[5];
  const float* f2b   = (const float*)d_in[6];
  const float* f3w1  = (const float*)d_in[7];
  const float* f3w2  = (const float*)d_in[8];
  const float* f3b   = (const float*)d_in[9];
  const float* f4w1  = (const float*)d_in[10];
  const float* f4w2  = (const float*)d_in[11];
  const float* f4b   = (const float*)d_in[12];
  const int B = in_sizes[0] / 784;           // 65536
  (void)n_in; (void)out_size;

  float* wsF   = (float*)d_ws;
  u16*  wfrag  = (u16*)((char*)d_ws + PREP_F*4);
  u16*  wsAct  = (u16*)((char*)d_ws + PREP_BYTES);

  k_prep<<<dim3(32), 256, 0, stream>>>(f1w1, f1w2, f2w1, wsF, wfrag);

  const float* w2g  = wsF + W2G_OFF;
  const float* w12g = wsF + W12G_OFF;

  const size_t perRow = 750 * sizeof(u16);   // act 405 | o2t 135 | h2t 135 | o3t 75
  int Rc = B;
  if (ws_size - PREP_BYTES < (size_t)B * perRow){
    size_t rows = (ws_size - PREP_BYTES) / perRow;
    Rc = (int)(rows & ~(size_t)511);
    if (Rc < 512) Rc = 512;
  }
  for (int base = 0; base < B; base += Rc){
    const int Bc = (B - base < Rc) ? (B - base) : Rc;
    u16* act = wsAct;
    u16* o2t = act + (size_t)405 * Bc;
    u16* h2t = o2t + (size_t)135 * Bc;
    u16* o3t = h2t + (size_t)135 * Bc;
    k_fc1a<<<dim3(Bc/256, 15), 256, 0, stream>>>(x, wfrag, act, base, Bc);
    k_fc1b<<<dim3(Bc/256, 15), 256, 0, stream>>>(w2g, f1b, act, Bc);
    k_fc2a<<<dim3(Bc/256, 15), 256, 0, stream>>>(act, w12g, o2t, Bc);
    k_fc2b<<<dim3(Bc/256, 15), 256, 0, stream>>>(o2t, f2w2, f2b, h2t, Bc);
    k_fc3a<<<dim3(Bc/256, 15), 256, 0, stream>>>(h2t, f3w1, o3t, Bc);
    k_fc3b4<<<dim3(Bc/256), 256, 0, stream>>>(o3t, f3w2, f3b,
                                              f4w1, f4w2, f4b, (float*)d_out, base, Bc);
  }
}